// Round 8
// baseline (3621.959 us; speedup 1.0000x reference)
//
#include <hip/hip_runtime.h>
#include <stdint.h>

typedef _Float16 f16x8 __attribute__((ext_vector_type(8)));
typedef _Float16 f16x4 __attribute__((ext_vector_type(4)));
typedef float    f32x4 __attribute__((ext_vector_type(4)));
typedef unsigned int u32x4v __attribute__((ext_vector_type(4)));

#define T_LEN 512
#define RLX   __ATOMIC_RELAXED
#define AGT   __HIP_MEMORY_SCOPE_AGENT

union HF8 { unsigned int u[4]; f16x8 v; };

// ---------------------------------------------------------------------------
// async global->LDS (16B/lane). LDS dest = wave-uniform base + lane*16.
// GLOBAL SOURCE IS PER-LANE: caller passes this lane's address.
// ---------------------------------------------------------------------------
__device__ __forceinline__ void gload_lds16(const void* gsrc, void* ldsdst) {
    auto g = (const __attribute__((address_space(1))) void*)(reinterpret_cast<uintptr_t>(gsrc));
    auto s = (__attribute__((address_space(3))) void*)(reinterpret_cast<uintptr_t>(ldsdst));
    __builtin_amdgcn_global_load_lds(g, s, 16, 0, 0);
}
__device__ __forceinline__ void wait_vm0() {
    asm volatile("s_waitcnt vmcnt(0)" ::: "memory");
    __builtin_amdgcn_sched_barrier(0);
}
__device__ __forceinline__ unsigned int pack_tag(float x, unsigned int tag) {
    union { _Float16 h; unsigned short s; } c; c.h = (_Float16)x;
    return ((unsigned int)c.s << 16) | tag;
}

// ---------------------------------------------------------------------------
// prep: f16 weights (Wci=[W_iz;W_in], Whc=[W_hz;W_hn]), bc=b_i+b_h,
// zero tagged hbuf (tag 0 = step-0 seed). Runs every launch (graph replays).
// ---------------------------------------------------------------------------
__global__ __launch_bounds__(256) void prep_misc(
    const float* __restrict__ W_iz, const float* __restrict__ W_in,
    const float* __restrict__ W_hz, const float* __restrict__ W_hn,
    const float* __restrict__ b_iz, const float* __restrict__ b_in,
    const float* __restrict__ b_hz, const float* __restrict__ b_hn,
    _Float16* __restrict__ Wci, _Float16* __restrict__ Whc,
    float* __restrict__ bc, unsigned int* __restrict__ hbuf32)
{
    const int tid = blockIdx.x * 256 + threadIdx.x;
    if (tid < 131072) {                      // 2 * 1024*512/8 weight vec units
        const bool is_h = tid >= 65536;
        const int u = tid & 65535;
        const int e = u * 8;
        const int row = e >> 9;
        const int k = e & 511;
        const float* s;
        if (!is_h) s = (row < 512) ? (W_iz + (size_t)row * 512 + k)
                                   : (W_in + (size_t)(row - 512) * 512 + k);
        else       s = (row < 512) ? (W_hz + (size_t)row * 512 + k)
                                   : (W_hn + (size_t)(row - 512) * 512 + k);
        f32x4 a = *(const f32x4*)s;
        f32x4 b = *(const f32x4*)(s + 4);
        f16x8 o;
        o[0] = (_Float16)a[0]; o[1] = (_Float16)a[1];
        o[2] = (_Float16)a[2]; o[3] = (_Float16)a[3];
        o[4] = (_Float16)b[0]; o[5] = (_Float16)b[1];
        o[6] = (_Float16)b[2]; o[7] = (_Float16)b[3];
        _Float16* d = is_h ? Whc : Wci;
        *(f16x8*)(d + e) = o;
    } else if (tid < 132096) {               // 1024 combined biases
        const int j2 = tid - 131072;
        bc[j2] = (j2 < 512) ? (b_iz[j2] + b_hz[j2]) : (b_in[j2 - 512] + b_hn[j2 - 512]);
    } else if (tid < 164864) {               // zero tagged hbuf: 131072 u32 / 4
        const int u = tid - 132096;
        u32x4v z = {0u, 0u, 0u, 0u};
        *(u32x4v*)(hbuf32 + (size_t)u * 4) = z;
    }
}

// ---------------------------------------------------------------------------
// Phase 1: input projections -> BLOCKED izin layout (f16, into d_out):
//   record (t, blk_s, gate) at byte ((t*128+blk_s)*2+gate)*1024 + lane*16
//   where scan WG blk_s=(b>>4)*16+w_s owns b-row b, j-cols w_s*32..+32.
// (UNCHANGED — verified in rounds 4/6.)
// ---------------------------------------------------------------------------
__global__ __launch_bounds__(256) void gemm_proj(
    const float* __restrict__ A,      // seq [65536][512] f32 (row = t*128+b)
    const _Float16* __restrict__ Bw,  // Wci [1024][512] f16
    const float* __restrict__ bc,     // [1024] f32
    _Float16* Co)                     // blocked izin (= d_out as f16)
{
    __shared__ _Float16 As[128 * 40];   // padded stride 40 f16
    __shared__ _Float16 Bs[128 * 32];   // linear (global_load_lds target)

    const int mt = blockIdx.x;          // = t
    const int nt = blockIdx.y;          // 0..7 (0-3: z gate, 4-7: n gate)
    const int m0 = mt * 128, n0 = nt * 128;
    const int tid = threadIdx.x;
    const int w = tid >> 6, l = tid & 63;
    const int wr = w >> 1, wc = w & 1;
    const int lrow = l & 15, lk = l >> 4;

    f32x4 acc[4][4] = {};

    const int arow = tid >> 1;
    const int acol = (tid & 1) * 16;

    for (int kt = 0; kt < 16; ++kt) {
        const int k0 = kt * 32;
        if (kt) __syncthreads();
        const float* as = A + (size_t)(m0 + arow) * 512 + k0 + acol;
        f32x4 a0 = *(const f32x4*)as;
        f32x4 a1 = *(const f32x4*)(as + 4);
        f32x4 a2 = *(const f32x4*)(as + 8);
        f32x4 a3 = *(const f32x4*)(as + 12);
        f16x8 h0, h1;
#pragma unroll
        for (int e = 0; e < 4; ++e) {
            h0[e] = (_Float16)a0[e]; h0[4 + e] = (_Float16)a1[e];
            h1[e] = (_Float16)a2[e]; h1[4 + e] = (_Float16)a3[e];
        }
        *(f16x8*)&As[arow * 40 + acol] = h0;
        *(f16x8*)&As[arow * 40 + acol + 8] = h1;
#pragma unroll
        for (int i = 0; i < 2; ++i) {
            const int chunk = w * 2 + i;
            const _Float16* gsrc =
                Bw + (size_t)(n0 + chunk * 16 + (l >> 2)) * 512 + k0 + (l & 3) * 8;
            gload_lds16(gsrc, &Bs[chunk * 512]);
        }
        __syncthreads();
        f16x8 af[4], bf[4];
#pragma unroll
        for (int i = 0; i < 4; ++i) {
            af[i] = *(const f16x8*)&As[(wr * 64 + i * 16 + lrow) * 40 + lk * 8];
            bf[i] = *(const f16x8*)&Bs[(wc * 64 + i * 16 + lrow) * 32 + lk * 8];
        }
#pragma unroll
        for (int mi = 0; mi < 4; ++mi)
#pragma unroll
            for (int ni = 0; ni < 4; ++ni)
                acc[mi][ni] = __builtin_amdgcn_mfma_f32_16x16x32_f16(
                    bf[ni], af[mi], acc[mi][ni], 0, 0, 0);
    }
    // epilogue: bias + cvt f16 + blocked store
    const int gate = nt >> 2;
#pragma unroll
    for (int mi = 0; mi < 4; ++mi) {
#pragma unroll
        for (int p = 0; p < 2; ++p) {
            const int j2q0 = n0 + wc * 64 + p * 32 + 4 * lk;
            const f32x4 b0 = *(const f32x4*)&bc[j2q0];
            const f32x4 b1 = *(const f32x4*)&bc[j2q0 + 16];
            f16x8 o;
#pragma unroll
            for (int r = 0; r < 4; ++r) {
                o[r]     = (_Float16)(acc[mi][2 * p][r]     + b0[r]);
                o[4 + r] = (_Float16)(acc[mi][2 * p + 1][r] + b1[r]);
            }
            const int blk_s = (wr * 4 + mi) * 16 + (nt & 3) * 4 + wc * 2 + p;
            _Float16* dst = Co + ((((size_t)mt * 128 + blk_s) * 2 + gate) * 512) + l * 8;
            *(f16x8*)dst = o;
        }
    }
}

// ---------------------------------------------------------------------------
// Phase 2: persistent scan — FLAGLESS, tagged data, per-slice verify.
// 128 WGs x 1 wave. group g = blk>>4 owns batch rows [16g,16g+16);
// slot w = blk&15 owns hidden cols [32w,32w+32), both gates.
// hbuf32[2][128][512] u32; each u32 = (f16 h << 16) | step_tag.
// Step t: burst-load ALL 16 k-slices (64 independent u64 agent atomics =
// one LLC RT), then per slice: verify 8 tags==t (retry = 4 u64 reload,
// 1KB/wave), unpack, 4 MFMA. Epilogue -> H[t] stores + izin DMA(t+2) ->
// counted vmcnt (drains the step-old DMA the publish licenses peers to
// clobber, NOT the just-issued ops) -> publish tagged h (4 u64, NO ack).
// Weights: 64KB LDS. izin: 4-slot x 2KB LDS ring (per-lane DMA src).
// ---------------------------------------------------------------------------
__global__ __launch_bounds__(64, 1) void gru_scan(
    const _Float16* __restrict__ Whc,   // [1024][512] f16
    const char* izb,                    // d_out bytes: blocked izin (aliases Hout)
    float* Hout,                        // d_out as f32 [t][b][j]
    unsigned int* hbuf32)               // [2][128][512] tagged u32
{
    __shared__ _Float16 wlds[64 * 512];   // 64 subtiles x 1KB = 64KB
    __shared__ _Float16 izlds[4 * 1024];  // 4 slots x 2KB ring

    const int blk = blockIdx.x;
    const int g = blk >> 4;
    const int w = blk & 15;
    const int l = threadIdx.x;
    const int lrow = l & 15, lk = l >> 4;
    const int j0 = w * 32;
    const int b = g * 16 + lrow;
    const size_t lb = (size_t)l * 16;     // per-lane byte offset for DMA source

    // ---- stage weights into LDS: subtile (gate, jt, s), lane i -> slot i
    for (int gate = 0; gate < 2; ++gate)
        for (int jt = 0; jt < 2; ++jt)
#pragma unroll
            for (int s = 0; s < 16; ++s) {
                const int sub = (gate * 2 + jt) * 16 + s;
                const _Float16* gsrc = Whc +
                    (size_t)(gate * 512 + j0 + jt * 16 + lrow) * 512 + s * 32 + lk * 8;
                gload_lds16(gsrc, &wlds[sub * 512]);
            }
    // ---- prefetch izin slots 0,1 (per-lane source addresses!)
    {
        const char* s0 = izb + (size_t)blk * 2048;
        gload_lds16(s0 + lb,        &izlds[0]);
        gload_lds16(s0 + 1024 + lb, &izlds[512]);
        const char* s1 = izb + 262144 + (size_t)blk * 2048;
        gload_lds16(s1 + lb,        &izlds[1024]);
        gload_lds16(s1 + 1024 + lb, &izlds[1536]);
    }
    wait_vm0();

    float hm0[4] = {0.f, 0.f, 0.f, 0.f};
    float hm1[4] = {0.f, 0.f, 0.f, 0.f};

    for (int t = 0; t < T_LEN; ++t) {
        const unsigned int tag = (unsigned int)t;           // expected tag this step
        const unsigned long long tp =
            (unsigned long long)tag * 0x0000000100000001ull;
        const unsigned long long* hr = (const unsigned long long*)
            (hbuf32 + (size_t)((t + 1) & 1) * 65536 + (size_t)b * 512);

        // ---- speculative burst: all 16 slices x 4 u64 (independent loads)
        unsigned long long q[16][4];
#pragma unroll
        for (int s = 0; s < 16; ++s) {
            const unsigned long long* p = hr + s * 16 + lk * 4;
            q[s][0] = __hip_atomic_load(p + 0, RLX, AGT);
            q[s][1] = __hip_atomic_load(p + 1, RLX, AGT);
            q[s][2] = __hip_atomic_load(p + 2, RLX, AGT);
            q[s][3] = __hip_atomic_load(p + 3, RLX, AGT);
        }

        // ---- per-slice verify -> unpack -> MFMA (4 tiles: z/n x jt0/jt1)
        f32x4 az0 = {0.f,0.f,0.f,0.f}, az1 = az0, an0 = az0, an1 = az0;
#pragma unroll
        for (int s = 0; s < 16; ++s) {
            while (true) {
                const unsigned long long acc =
                    (q[s][0] ^ tp) | (q[s][1] ^ tp) | (q[s][2] ^ tp) | (q[s][3] ^ tp);
                if (__all((acc & 0x0000FFFF0000FFFFull) == 0)) break;
                const unsigned long long* p = hr + s * 16 + lk * 4;
                q[s][0] = __hip_atomic_load(p + 0, RLX, AGT);
                q[s][1] = __hip_atomic_load(p + 1, RLX, AGT);
                q[s][2] = __hip_atomic_load(p + 2, RLX, AGT);
                q[s][3] = __hip_atomic_load(p + 3, RLX, AGT);
            }
            HF8 hf;
#pragma unroll
            for (int jj = 0; jj < 4; ++jj) {
                const unsigned int lo = (unsigned int)q[s][jj];
                const unsigned int hi = (unsigned int)(q[s][jj] >> 32);
                hf.u[jj] = (lo >> 16) | (hi & 0xFFFF0000u);
            }
            const f16x8 wz0 = *(const f16x8*)&wlds[(0 * 16 + s) * 512 + l * 8];
            const f16x8 wz1 = *(const f16x8*)&wlds[(1 * 16 + s) * 512 + l * 8];
            const f16x8 wn0 = *(const f16x8*)&wlds[(2 * 16 + s) * 512 + l * 8];
            const f16x8 wn1 = *(const f16x8*)&wlds[(3 * 16 + s) * 512 + l * 8];
            az0 = __builtin_amdgcn_mfma_f32_16x16x32_f16(wz0, hf.v, az0, 0, 0, 0);
            az1 = __builtin_amdgcn_mfma_f32_16x16x32_f16(wz1, hf.v, az1, 0, 0, 0);
            an0 = __builtin_amdgcn_mfma_f32_16x16x32_f16(wn0, hf.v, an0, 0, 0, 0);
            an1 = __builtin_amdgcn_mfma_f32_16x16x32_f16(wn1, hf.v, an1, 0, 0, 0);
        }

        // ---- izin for this step from LDS ring
        const f16x8 zrec = *(const f16x8*)&izlds[(t & 3) * 1024 + l * 8];
        const f16x8 nrec = *(const f16x8*)&izlds[(t & 3) * 1024 + 512 + l * 8];

        // ---- gates + state update (f32)
        u32x4v th0, th1;
        f32x4 Hv0, Hv1;
#pragma unroll
        for (int r = 0; r < 4; ++r) {
            float zpre = az0[r] + (float)zrec[r];
            float npre = an0[r] + (float)nrec[r];
            zpre = fminf(fmaxf(zpre, -30.f), 30.f);
            const float z = 1.f / (1.f + __expf(-zpre));
            npre = fminf(fmaxf(npre, -15.f), 15.f);
            const float e2 = __expf(2.f * npre);
            const float n = (e2 - 1.f) / (e2 + 1.f);
            hm0[r] = (1.f - z) * n + z * hm0[r];
            Hv0[r] = hm0[r];
            th0[r] = pack_tag(hm0[r], tag + 1);

            float zpre1 = az1[r] + (float)zrec[4 + r];
            float npre1 = an1[r] + (float)nrec[4 + r];
            zpre1 = fminf(fmaxf(zpre1, -30.f), 30.f);
            const float z1 = 1.f / (1.f + __expf(-zpre1));
            npre1 = fminf(fmaxf(npre1, -15.f), 15.f);
            const float e21 = __expf(2.f * npre1);
            const float n1 = (e21 - 1.f) / (e21 + 1.f);
            hm1[r] = (1.f - z1) * n1 + z1 * hm1[r];
            Hv1[r] = hm1[r];
            th1[r] = pack_tag(hm1[r], tag + 1);
        }

        // ---- H[t] stores (plain, local L2 write-back; NOT drained below)
        *(f32x4*)&Hout[(size_t)t * 65536 + (size_t)b * 512 + j0 + 4 * lk] = Hv0;
        *(f32x4*)&Hout[(size_t)t * 65536 + (size_t)b * 512 + j0 + 16 + 4 * lk] = Hv1;
        __builtin_amdgcn_sched_barrier(0);

        if (t < T_LEN - 1) {
            // ---- izin DMA(t+2) + counted drain, then fire-and-forget publish.
            // vmcnt(N) excludes the N newest ops (H stores + this DMA) but
            // drains DMA(t+1) from last step — the publish below licenses
            // peers to clobber izin[t+1] bytes with H[t+1].
            if (t + 2 < T_LEN) {
                const char* src = izb + (size_t)(t + 2) * 262144 + (size_t)blk * 2048;
                gload_lds16(src + lb,        &izlds[((t + 2) & 3) * 1024]);
                gload_lds16(src + 1024 + lb, &izlds[((t + 2) & 3) * 1024 + 512]);
                __builtin_amdgcn_sched_barrier(0);
                asm volatile("s_waitcnt vmcnt(4)" ::: "memory");
            } else {
                asm volatile("s_waitcnt vmcnt(2)" ::: "memory");
            }
            __builtin_amdgcn_sched_barrier(0);

            // ---- publish tagged h_{t+1}: quad0 at u32 j0+4lk, quad1 at +16 u32
            unsigned long long* hw = (unsigned long long*)
                (hbuf32 + (size_t)(t & 1) * 65536 + (size_t)b * 512 + j0 + 4 * lk);
            const unsigned long long q00 = ((unsigned long long)th0[1] << 32) | th0[0];
            const unsigned long long q01 = ((unsigned long long)th0[3] << 32) | th0[2];
            const unsigned long long q10 = ((unsigned long long)th1[1] << 32) | th1[0];
            const unsigned long long q11 = ((unsigned long long)th1[3] << 32) | th1[2];
            __hip_atomic_store(hw + 0, q00, RLX, AGT);
            __hip_atomic_store(hw + 1, q01, RLX, AGT);
            __hip_atomic_store(hw + 8, q10, RLX, AGT);
            __hip_atomic_store(hw + 9, q11, RLX, AGT);
        }
    }
}

// ---------------------------------------------------------------------------
extern "C" void kernel_launch(void* const* d_in, const int* in_sizes, int n_in,
                              void* d_out, int out_size, void* d_ws, size_t ws_size,
                              hipStream_t stream) {
    (void)in_sizes; (void)n_in; (void)out_size; (void)ws_size;
    const float* seq  = (const float*)d_in[0];
    const float* W_iz = (const float*)d_in[1];
    const float* b_iz = (const float*)d_in[2];
    const float* W_in = (const float*)d_in[3];
    const float* b_in = (const float*)d_in[4];
    const float* W_hz = (const float*)d_in[5];
    const float* b_hz = (const float*)d_in[6];
    const float* W_hn = (const float*)d_in[7];
    const float* b_hn = (const float*)d_in[8];

    char* ws = (char*)d_ws;                                 // total use: ~2.6 MB
    _Float16*     Wci    = (_Float16*)(ws);                 // 1,048,576 B
    _Float16*     Whc    = (_Float16*)(ws + 1048576);       // 1,048,576 B
    float*        bc     = (float*)   (ws + 2097152);       //     4,096 B
    unsigned int* hbuf32 = (unsigned int*)(ws + 2101248);   //   524,288 B tagged

    prep_misc<<<644, 256, 0, stream>>>(W_iz, W_in, W_hz, W_hn,
                                       b_iz, b_in, b_hz, b_hn,
                                       Wci, Whc, bc, hbuf32);
    gemm_proj<<<dim3(512, 8), 256, 0, stream>>>(seq, Wci, bc, (_Float16*)d_out);
    gru_scan<<<128, 64, 0, stream>>>(Whc, (const char*)d_out, (float*)d_out, hbuf32);
}

// Round 9
// 2076.216 us; speedup vs baseline: 1.7445x; 1.7445x over previous
//
#include <hip/hip_runtime.h>
#include <stdint.h>

typedef _Float16 f16x8 __attribute__((ext_vector_type(8)));
typedef _Float16 f16x4 __attribute__((ext_vector_type(4)));
typedef float    f32x4 __attribute__((ext_vector_type(4)));
typedef unsigned int u32x4v __attribute__((ext_vector_type(4)));

#define T_LEN 512
#define RLX   __ATOMIC_RELAXED
#define AGT   __HIP_MEMORY_SCOPE_AGENT

union PK4 { _Float16 h[4]; unsigned long long q; };
union QZ  { unsigned long long q; f16x4 v; };

// ---------------------------------------------------------------------------
// async global->LDS (16B/lane). LDS dest = wave-uniform base + lane*16.
// GLOBAL SOURCE IS PER-LANE.
// ---------------------------------------------------------------------------
__device__ __forceinline__ void gload_lds16(const void* gsrc, void* ldsdst) {
    auto g = (const __attribute__((address_space(1))) void*)(reinterpret_cast<uintptr_t>(gsrc));
    auto s = (__attribute__((address_space(3))) void*)(reinterpret_cast<uintptr_t>(ldsdst));
    __builtin_amdgcn_global_load_lds(g, s, 16, 0, 0);
}

// ---------------------------------------------------------------------------
// prep: f16 weights (Wci=[W_iz;W_in], Whc=[W_hz;W_hn]), bc=b_i+b_h,
// zero tagged hbuf (tag 0 = step-0 seed, h_0=0). Runs every launch (replays).
// ---------------------------------------------------------------------------
__global__ __launch_bounds__(256) void prep_misc(
    const float* __restrict__ W_iz, const float* __restrict__ W_in,
    const float* __restrict__ W_hz, const float* __restrict__ W_hn,
    const float* __restrict__ b_iz, const float* __restrict__ b_in,
    const float* __restrict__ b_hz, const float* __restrict__ b_hn,
    _Float16* __restrict__ Wci, _Float16* __restrict__ Whc,
    float* __restrict__ bc, unsigned int* __restrict__ hbuf32)
{
    const int tid = blockIdx.x * 256 + threadIdx.x;
    if (tid < 131072) {                      // 2 * 1024*512/8 weight vec units
        const bool is_h = tid >= 65536;
        const int u = tid & 65535;
        const int e = u * 8;
        const int row = e >> 9;
        const int k = e & 511;
        const float* s;
        if (!is_h) s = (row < 512) ? (W_iz + (size_t)row * 512 + k)
                                   : (W_in + (size_t)(row - 512) * 512 + k);
        else       s = (row < 512) ? (W_hz + (size_t)row * 512 + k)
                                   : (W_hn + (size_t)(row - 512) * 512 + k);
        f32x4 a = *(const f32x4*)s;
        f32x4 b = *(const f32x4*)(s + 4);
        f16x8 o;
        o[0] = (_Float16)a[0]; o[1] = (_Float16)a[1];
        o[2] = (_Float16)a[2]; o[3] = (_Float16)a[3];
        o[4] = (_Float16)b[0]; o[5] = (_Float16)b[1];
        o[6] = (_Float16)b[2]; o[7] = (_Float16)b[3];
        _Float16* d = is_h ? Whc : Wci;
        *(f16x8*)(d + e) = o;
    } else if (tid < 132096) {               // 1024 combined biases
        const int j2 = tid - 131072;
        bc[j2] = (j2 < 512) ? (b_iz[j2] + b_hz[j2]) : (b_in[j2 - 512] + b_hn[j2 - 512]);
    } else if (tid < 164864) {               // zero tagged hbuf: 131072 u32 / 4
        const int u = tid - 132096;
        u32x4v z = {0u, 0u, 0u, 0u};
        *(u32x4v*)(hbuf32 + (size_t)u * 4) = z;
    }
}

// ---------------------------------------------------------------------------
// Phase 1: input projections -> BLOCKED izin records (f16, into d_out):
//   record (t, blk_s) = 2KB at byte (t*128+blk_s)*2048: [z 1KB][n 1KB];
//   in-gate: lane l (64) x 16B = [quad j0+4*(l>>4), quad j0+16+4*(l>>4)],
//   b = 16*(blk_s>>4) + (l&15), j0 = 32*(blk_s&15).
// (UNCHANGED — verified rounds 4/6/8.)
// ---------------------------------------------------------------------------
__global__ __launch_bounds__(256) void gemm_proj(
    const float* __restrict__ A,      // seq [65536][512] f32 (row = t*128+b)
    const _Float16* __restrict__ Bw,  // Wci [1024][512] f16
    const float* __restrict__ bc,     // [1024] f32
    _Float16* Co)                     // blocked izin (= d_out as f16)
{
    __shared__ _Float16 As[128 * 40];   // padded stride 40 f16
    __shared__ _Float16 Bs[128 * 32];   // linear (global_load_lds target)

    const int mt = blockIdx.x;          // = t
    const int nt = blockIdx.y;          // 0..7 (0-3: z gate, 4-7: n gate)
    const int m0 = mt * 128, n0 = nt * 128;
    const int tid = threadIdx.x;
    const int w = tid >> 6, l = tid & 63;
    const int wr = w >> 1, wc = w & 1;
    const int lrow = l & 15, lk = l >> 4;

    f32x4 acc[4][4] = {};

    const int arow = tid >> 1;
    const int acol = (tid & 1) * 16;

    for (int kt = 0; kt < 16; ++kt) {
        const int k0 = kt * 32;
        if (kt) __syncthreads();
        const float* as = A + (size_t)(m0 + arow) * 512 + k0 + acol;
        f32x4 a0 = *(const f32x4*)as;
        f32x4 a1 = *(const f32x4*)(as + 4);
        f32x4 a2 = *(const f32x4*)(as + 8);
        f32x4 a3 = *(const f32x4*)(as + 12);
        f16x8 h0, h1;
#pragma unroll
        for (int e = 0; e < 4; ++e) {
            h0[e] = (_Float16)a0[e]; h0[4 + e] = (_Float16)a1[e];
            h1[e] = (_Float16)a2[e]; h1[4 + e] = (_Float16)a3[e];
        }
        *(f16x8*)&As[arow * 40 + acol] = h0;
        *(f16x8*)&As[arow * 40 + acol + 8] = h1;
#pragma unroll
        for (int i = 0; i < 2; ++i) {
            const int chunk = w * 2 + i;
            const _Float16* gsrc =
                Bw + (size_t)(n0 + chunk * 16 + (l >> 2)) * 512 + k0 + (l & 3) * 8;
            gload_lds16(gsrc, &Bs[chunk * 512]);
        }
        __syncthreads();
        f16x8 af[4], bf[4];
#pragma unroll
        for (int i = 0; i < 4; ++i) {
            af[i] = *(const f16x8*)&As[(wr * 64 + i * 16 + lrow) * 40 + lk * 8];
            bf[i] = *(const f16x8*)&Bs[(wc * 64 + i * 16 + lrow) * 32 + lk * 8];
        }
#pragma unroll
        for (int mi = 0; mi < 4; ++mi)
#pragma unroll
            for (int ni = 0; ni < 4; ++ni)
                acc[mi][ni] = __builtin_amdgcn_mfma_f32_16x16x32_f16(
                    bf[ni], af[mi], acc[mi][ni], 0, 0, 0);
    }
    // epilogue: bias + cvt f16 + blocked store
    const int gate = nt >> 2;
#pragma unroll
    for (int mi = 0; mi < 4; ++mi) {
#pragma unroll
        for (int p = 0; p < 2; ++p) {
            const int j2q0 = n0 + wc * 64 + p * 32 + 4 * lk;
            const f32x4 b0 = *(const f32x4*)&bc[j2q0];
            const f32x4 b1 = *(const f32x4*)&bc[j2q0 + 16];
            f16x8 o;
#pragma unroll
            for (int r = 0; r < 4; ++r) {
                o[r]     = (_Float16)(acc[mi][2 * p][r]     + b0[r]);
                o[4 + r] = (_Float16)(acc[mi][2 * p + 1][r] + b1[r]);
            }
            const int blk_s = (wr * 4 + mi) * 16 + (nt & 3) * 4 + wc * 2 + p;
            _Float16* dst = Co + ((((size_t)mt * 128 + blk_s) * 2 + gate) * 512) + l * 8;
            *(f16x8*)dst = o;
        }
    }
}

// ---------------------------------------------------------------------------
// Phase 2: persistent scan — 32 WGs x 8 waves (512 thr).
// Slot-major mapping: g = blk&7 (batch rows [16g,+16)), slot = blk>>3
// (j-cols [128*slot,+128)) -> a group's 4 WGs are blk, blk+8, +16, +24
// (same XCD under round-robin dispatch).
// Wave wv owns j-tile [128*slot + 16*wv, +16), both gates; weights in
// REGISTERS (32 x f16x8 = 128 VGPR/lane).
// h exchange: hbuf32[2][128][512] tagged u32 ((h<<16)|step_tag).
//   h_t lives at parity (t+1)&1 with tag t. Publish = fire-and-forget.
// Per step: 6 tagged u64 partner loads/thread (retry granule = 1 quad),
// unpack -> XOR-swizzled LDS stage (own chunk staged by epilogue of t-1),
// syncthreads, 16 swizzled ds_read_b128 + 32 MFMA, gates, own LDS stage,
// vmcnt(0) [drains 2 izin loads issued pre-barrier], publish, H[t] store.
// Safety: tag-t visibility on ALL partner quads before barrier => peers'
// izin[t] reads retired => H[t] may clobber izin[t]; izin[t+1] loads drain
// before tag-(t+1) publish => peers' H[t+1] can't clobber them.
// ---------------------------------------------------------------------------
__global__ __launch_bounds__(512, 2) void gru_scan(
    const _Float16* __restrict__ Whc,   // [1024][512] f16
    const char* izb,                    // d_out bytes: blocked izin (aliases Hout)
    float* Hout,                        // d_out as f32 [t][b][j]
    unsigned int* hbuf32)               // [2][128][512] tagged u32
{
    __shared__ _Float16 hlds[2 * 16 * 512];   // 32 KB, XOR-swizzled (^(b&7)<<3)

    const int blk  = blockIdx.x;        // 0..31
    const int g    = blk & 7;
    const int slot = blk >> 3;          // 0..3
    const int tid  = threadIdx.x;
    const int wv   = tid >> 6;          // wave 0..7
    const int l    = tid & 63;
    const int lrow = l & 15, lk = l >> 4;
    const int jbase = slot * 128 + wv * 16;
    const int jq    = jbase + 4 * lk;            // lane's j quad base
    const int bg    = 16 * g + lrow;             // lane's global b (epilogue/frag row)
    const int blk_s = 16 * g + 4 * slot + (wv >> 1);  // izin record index
    const int stage_b = tid >> 5;                // 0..15 (partner staging b)
    const int stage_jq = 4 * (tid & 31);         // 0..124 (partner staging j-quad)

    // ---- register-resident weights: rows jbase+lrow (z), 512+jbase+lrow (n)
    f16x8 wz[16], wn[16];
#pragma unroll
    for (int s = 0; s < 16; ++s) {
        wz[s] = *(const f16x8*)&Whc[(size_t)(jbase + lrow) * 512 + s * 32 + lk * 8];
        wn[s] = *(const f16x8*)&Whc[(size_t)(512 + jbase + lrow) * 512 + s * 32 + lk * 8];
    }

    // ---- seed own h_0 = 0 into hlds[0] (parity of step 0)
    *(unsigned long long*)&hlds[(lrow * 512 + jq) ^ ((lrow & 7) << 3)] = 0ull;

    // ---- izin[0] prefetch (plain u64 loads; gemm_proj wrote before launch)
    QZ pz, pn, npz, npn;
    {
        const char* rec = izb + ((size_t)0 * 128 + blk_s) * 2048 + l * 16 + (wv & 1) * 8;
        pz.q = *(const unsigned long long*)rec;
        pn.q = *(const unsigned long long*)(rec + 1024);
    }

    float hm[4] = {0.f, 0.f, 0.f, 0.f};   // h[bg][jq+r] master (f32)

    for (int t = 0; t < T_LEN; ++t) {
        const int par = (t + 1) & 1;           // parity holding h_t
        const int lp  = t & 1;                 // LDS buffer for h_t
        const unsigned long long tp =
            (unsigned long long)(unsigned)t | ((unsigned long long)(unsigned)t << 32);

        // ---- partner tagged loads: 3 quads/thread (one per partner slot)
        const unsigned long long* hb64 =
            (const unsigned long long*)(hbuf32 + (size_t)par * 65536);
        unsigned long long q0[3], q1[3];
        int pix[3];
#pragma unroll
        for (int i = 0; i < 3; ++i) {
            const int s_i = (slot + 1 + i) & 3;
            const int u32i = (16 * g + stage_b) * 512 + s_i * 128 + stage_jq;
            pix[i] = u32i >> 1;
            q0[i] = __hip_atomic_load(hb64 + pix[i],     RLX, AGT);
            q1[i] = __hip_atomic_load(hb64 + pix[i] + 1, RLX, AGT);
        }
#pragma unroll
        for (int i = 0; i < 3; ++i) {
            while (true) {
                const unsigned long long x = (q0[i] ^ tp) | (q1[i] ^ tp);
                if (__all((x & 0x0000FFFF0000FFFFull) == 0)) break;
                q0[i] = __hip_atomic_load(hb64 + pix[i],     RLX, AGT);
                q1[i] = __hip_atomic_load(hb64 + pix[i] + 1, RLX, AGT);
            }
        }
        // ---- unpack (strip tags) + swizzled LDS stage
#pragma unroll
        for (int i = 0; i < 3; ++i) {
            const int s_i = (slot + 1 + i) & 3;
            const unsigned int w0 = ((unsigned int)(q0[i] >> 16)) & 0xFFFFu;
            const unsigned int w1 = (unsigned int)(q0[i] >> 48);
            const unsigned int w2 = ((unsigned int)(q1[i] >> 16)) & 0xFFFFu;
            const unsigned int w3 = (unsigned int)(q1[i] >> 48);
            const unsigned long long out =
                (unsigned long long)(w0 | (w1 << 16)) |
                ((unsigned long long)(w2 | (w3 << 16)) << 32);
            const int idx = (lp * 8192 + stage_b * 512 + s_i * 128 + stage_jq)
                            ^ ((stage_b & 7) << 3);
            *(unsigned long long*)&hlds[idx] = out;
        }

        // ---- izin[t+1] loads (issued now; drained by vmcnt(0) pre-publish)
        if (t + 1 < T_LEN) {
            const char* rec = izb + ((size_t)(t + 1) * 128 + blk_s) * 2048
                              + l * 16 + (wv & 1) * 8;
            npz.q = *(const unsigned long long*)rec;
            npn.q = *(const unsigned long long*)(rec + 1024);
        }
        __builtin_amdgcn_sched_barrier(0);

        __syncthreads();

        // ---- MFMA: 2 tiles (z, n) x 16 k-slices; B-frags from swizzled LDS
        f32x4 az = {0.f, 0.f, 0.f, 0.f}, an = {0.f, 0.f, 0.f, 0.f};
        const int hbase = lp * 8192 + lrow * 512;
        const int sw = (lrow & 7) << 3;
#pragma unroll
        for (int s = 0; s < 16; ++s) {
            const f16x8 hf = *(const f16x8*)&hlds[(hbase + s * 32 + lk * 8) ^ sw];
            az = __builtin_amdgcn_mfma_f32_16x16x32_f16(wz[s], hf, az, 0, 0, 0);
            an = __builtin_amdgcn_mfma_f32_16x16x32_f16(wn[s], hf, an, 0, 0, 0);
        }

        // ---- gates + state update (f32)
        PK4 own;
        f32x4 Hv;
#pragma unroll
        for (int r = 0; r < 4; ++r) {
            float zpre = az[r] + (float)pz.v[r];
            float npre = an[r] + (float)pn.v[r];
            zpre = fminf(fmaxf(zpre, -30.f), 30.f);
            const float z = 1.f / (1.f + __expf(-zpre));
            npre = fminf(fmaxf(npre, -15.f), 15.f);
            const float e2 = __expf(2.f * npre);
            const float n = (e2 - 1.f) / (e2 + 1.f);
            hm[r] = (1.f - z) * n + z * hm[r];
            Hv[r] = hm[r];
            own.h[r] = (_Float16)hm[r];
        }

        // ---- stage own h_{t+1} chunk for next step (LDS parity (t+1)&1)
        *(unsigned long long*)
            &hlds[(((t + 1) & 1) * 8192 + lrow * 512 + jq) ^ ((lrow & 7) << 3)] = own.q;

        if (t < T_LEN - 1) {
            // ---- drain izin[t+1] (only outstanding VMEM; cheap), then publish
            asm volatile("s_waitcnt vmcnt(0)" ::: "memory");
            __builtin_amdgcn_sched_barrier(0);
            const unsigned long long tagp =
                (unsigned long long)(unsigned)(t + 1) |
                ((unsigned long long)(unsigned)(t + 1) << 32);
            const unsigned long long d0 =
                ((own.q & 0xFFFFull) << 16) |
                (((own.q >> 16) & 0xFFFFull) << 48) | tagp;
            const unsigned long long d1 =
                (((own.q >> 32) & 0xFFFFull) << 16) |
                (((own.q >> 48) & 0xFFFFull) << 48) | tagp;
            unsigned long long* hw = (unsigned long long*)
                (hbuf32 + (size_t)(t & 1) * 65536 + (size_t)bg * 512 + jq);
            __hip_atomic_store(hw,     d0, RLX, AGT);
            __hip_atomic_store(hw + 1, d1, RLX, AGT);
        }

        // ---- H[t] store (fire-and-forget; safe: all tags==t seen pre-barrier)
        *(f32x4*)&Hout[(size_t)t * 65536 + (size_t)bg * 512 + jq] = Hv;

        pz = npz; pn = npn;
    }
}

// ---------------------------------------------------------------------------
extern "C" void kernel_launch(void* const* d_in, const int* in_sizes, int n_in,
                              void* d_out, int out_size, void* d_ws, size_t ws_size,
                              hipStream_t stream) {
    (void)in_sizes; (void)n_in; (void)out_size; (void)ws_size;
    const float* seq  = (const float*)d_in[0];
    const float* W_iz = (const float*)d_in[1];
    const float* b_iz = (const float*)d_in[2];
    const float* W_in = (const float*)d_in[3];
    const float* b_in = (const float*)d_in[4];
    const float* W_hz = (const float*)d_in[5];
    const float* b_hz = (const float*)d_in[6];
    const float* W_hn = (const float*)d_in[7];
    const float* b_hn = (const float*)d_in[8];

    char* ws = (char*)d_ws;                                 // total use: ~2.6 MB
    _Float16*     Wci    = (_Float16*)(ws);                 // 1,048,576 B
    _Float16*     Whc    = (_Float16*)(ws + 1048576);       // 1,048,576 B
    float*        bc     = (float*)   (ws + 2097152);       //     4,096 B
    unsigned int* hbuf32 = (unsigned int*)(ws + 2101248);   //   524,288 B tagged

    prep_misc<<<644, 256, 0, stream>>>(W_iz, W_in, W_hz, W_hn,
                                       b_iz, b_in, b_hz, b_hn,
                                       Wci, Whc, bc, hbuf32);
    gemm_proj<<<dim3(512, 8), 256, 0, stream>>>(seq, Wci, bc, (_Float16*)d_out);
    gru_scan<<<32, 512, 0, stream>>>(Whc, (const char*)d_out, (float*)d_out, hbuf32);
}

// Round 10
// 2016.540 us; speedup vs baseline: 1.7961x; 1.0296x over previous
//
#include <hip/hip_runtime.h>
#include <stdint.h>

typedef _Float16 f16x8 __attribute__((ext_vector_type(8)));
typedef _Float16 f16x4 __attribute__((ext_vector_type(4)));
typedef float    f32x4 __attribute__((ext_vector_type(4)));
typedef unsigned int u32x4v __attribute__((ext_vector_type(4)));

#define T_LEN 512
#define RLX   __ATOMIC_RELAXED
#define AGT   __HIP_MEMORY_SCOPE_AGENT

union PK4 { _Float16 h[4]; unsigned long long q; };
union QZ  { unsigned long long q; f16x4 v; };

// ---------------------------------------------------------------------------
// async global->LDS (16B/lane). LDS dest = wave-uniform base + lane*16.
// GLOBAL SOURCE IS PER-LANE.
// ---------------------------------------------------------------------------
__device__ __forceinline__ void gload_lds16(const void* gsrc, void* ldsdst) {
    auto g = (const __attribute__((address_space(1))) void*)(reinterpret_cast<uintptr_t>(gsrc));
    auto s = (__attribute__((address_space(3))) void*)(reinterpret_cast<uintptr_t>(ldsdst));
    __builtin_amdgcn_global_load_lds(g, s, 16, 0, 0);
}

// ---------------------------------------------------------------------------
// prep: f16 weights (Wci=[W_iz;W_in], Whc=[W_hz;W_hn]), bc=b_i+b_h,
// zero tagged hbuf (tag 0 = step-0 seed, h_0=0). Runs every launch (replays).
// ---------------------------------------------------------------------------
__global__ __launch_bounds__(256) void prep_misc(
    const float* __restrict__ W_iz, const float* __restrict__ W_in,
    const float* __restrict__ W_hz, const float* __restrict__ W_hn,
    const float* __restrict__ b_iz, const float* __restrict__ b_in,
    const float* __restrict__ b_hz, const float* __restrict__ b_hn,
    _Float16* __restrict__ Wci, _Float16* __restrict__ Whc,
    float* __restrict__ bc, unsigned int* __restrict__ hbuf32)
{
    const int tid = blockIdx.x * 256 + threadIdx.x;
    if (tid < 131072) {                      // 2 * 1024*512/8 weight vec units
        const bool is_h = tid >= 65536;
        const int u = tid & 65535;
        const int e = u * 8;
        const int row = e >> 9;
        const int k = e & 511;
        const float* s;
        if (!is_h) s = (row < 512) ? (W_iz + (size_t)row * 512 + k)
                                   : (W_in + (size_t)(row - 512) * 512 + k);
        else       s = (row < 512) ? (W_hz + (size_t)row * 512 + k)
                                   : (W_hn + (size_t)(row - 512) * 512 + k);
        f32x4 a = *(const f32x4*)s;
        f32x4 b = *(const f32x4*)(s + 4);
        f16x8 o;
        o[0] = (_Float16)a[0]; o[1] = (_Float16)a[1];
        o[2] = (_Float16)a[2]; o[3] = (_Float16)a[3];
        o[4] = (_Float16)b[0]; o[5] = (_Float16)b[1];
        o[6] = (_Float16)b[2]; o[7] = (_Float16)b[3];
        _Float16* d = is_h ? Whc : Wci;
        *(f16x8*)(d + e) = o;
    } else if (tid < 132096) {               // 1024 combined biases
        const int j2 = tid - 131072;
        bc[j2] = (j2 < 512) ? (b_iz[j2] + b_hz[j2]) : (b_in[j2 - 512] + b_hn[j2 - 512]);
    } else if (tid < 164864) {               // zero tagged hbuf: 131072 u32 / 4
        const int u = tid - 132096;
        u32x4v z = {0u, 0u, 0u, 0u};
        *(u32x4v*)(hbuf32 + (size_t)u * 4) = z;
    }
}

// ---------------------------------------------------------------------------
// Phase 1: input projections -> BLOCKED izin records (f16, into d_out):
//   record (t, blk_s) = 2KB at byte (t*128+blk_s)*2048: [z 1KB][n 1KB];
//   in-gate: lane l (64) x 16B = [quad j0+4*(l>>4), quad j0+16+4*(l>>4)],
//   b = 16*(blk_s>>4) + (l&15), j0 = 32*(blk_s&15).
// (UNCHANGED — verified rounds 4/6/8/9.)
// ---------------------------------------------------------------------------
__global__ __launch_bounds__(256) void gemm_proj(
    const float* __restrict__ A,      // seq [65536][512] f32 (row = t*128+b)
    const _Float16* __restrict__ Bw,  // Wci [1024][512] f16
    const float* __restrict__ bc,     // [1024] f32
    _Float16* Co)                     // blocked izin (= d_out as f16)
{
    __shared__ _Float16 As[128 * 40];   // padded stride 40 f16
    __shared__ _Float16 Bs[128 * 32];   // linear (global_load_lds target)

    const int mt = blockIdx.x;          // = t
    const int nt = blockIdx.y;          // 0..7 (0-3: z gate, 4-7: n gate)
    const int m0 = mt * 128, n0 = nt * 128;
    const int tid = threadIdx.x;
    const int w = tid >> 6, l = tid & 63;
    const int wr = w >> 1, wc = w & 1;
    const int lrow = l & 15, lk = l >> 4;

    f32x4 acc[4][4] = {};

    const int arow = tid >> 1;
    const int acol = (tid & 1) * 16;

    for (int kt = 0; kt < 16; ++kt) {
        const int k0 = kt * 32;
        if (kt) __syncthreads();
        const float* as = A + (size_t)(m0 + arow) * 512 + k0 + acol;
        f32x4 a0 = *(const f32x4*)as;
        f32x4 a1 = *(const f32x4*)(as + 4);
        f32x4 a2 = *(const f32x4*)(as + 8);
        f32x4 a3 = *(const f32x4*)(as + 12);
        f16x8 h0, h1;
#pragma unroll
        for (int e = 0; e < 4; ++e) {
            h0[e] = (_Float16)a0[e]; h0[4 + e] = (_Float16)a1[e];
            h1[e] = (_Float16)a2[e]; h1[4 + e] = (_Float16)a3[e];
        }
        *(f16x8*)&As[arow * 40 + acol] = h0;
        *(f16x8*)&As[arow * 40 + acol + 8] = h1;
#pragma unroll
        for (int i = 0; i < 2; ++i) {
            const int chunk = w * 2 + i;
            const _Float16* gsrc =
                Bw + (size_t)(n0 + chunk * 16 + (l >> 2)) * 512 + k0 + (l & 3) * 8;
            gload_lds16(gsrc, &Bs[chunk * 512]);
        }
        __syncthreads();
        f16x8 af[4], bf[4];
#pragma unroll
        for (int i = 0; i < 4; ++i) {
            af[i] = *(const f16x8*)&As[(wr * 64 + i * 16 + lrow) * 40 + lk * 8];
            bf[i] = *(const f16x8*)&Bs[(wc * 64 + i * 16 + lrow) * 32 + lk * 8];
        }
#pragma unroll
        for (int mi = 0; mi < 4; ++mi)
#pragma unroll
            for (int ni = 0; ni < 4; ++ni)
                acc[mi][ni] = __builtin_amdgcn_mfma_f32_16x16x32_f16(
                    bf[ni], af[mi], acc[mi][ni], 0, 0, 0);
    }
    // epilogue: bias + cvt f16 + blocked store
    const int gate = nt >> 2;
#pragma unroll
    for (int mi = 0; mi < 4; ++mi) {
#pragma unroll
        for (int p = 0; p < 2; ++p) {
            const int j2q0 = n0 + wc * 64 + p * 32 + 4 * lk;
            const f32x4 b0 = *(const f32x4*)&bc[j2q0];
            const f32x4 b1 = *(const f32x4*)&bc[j2q0 + 16];
            f16x8 o;
#pragma unroll
            for (int r = 0; r < 4; ++r) {
                o[r]     = (_Float16)(acc[mi][2 * p][r]     + b0[r]);
                o[4 + r] = (_Float16)(acc[mi][2 * p + 1][r] + b1[r]);
            }
            const int blk_s = (wr * 4 + mi) * 16 + (nt & 3) * 4 + wc * 2 + p;
            _Float16* dst = Co + ((((size_t)mt * 128 + blk_s) * 2 + gate) * 512) + l * 8;
            *(f16x8*)dst = o;
        }
    }
}

// ---------------------------------------------------------------------------
// Phase 2: persistent scan — 32 WGs x 8 waves (512 thr).
// IDENTICAL structure to round 9 except:
//  (a) __launch_bounds__(512, 1): VGPR cap >= 256 so the 128-VGPR weight
//      arrays stay register-resident (round 9's (512,2) made the allocator
//      spill them to scratch -> per-step L2 reloads; VGPR_Count was 96).
//  (b) izin[t+1] loads issued at the TOP of the step (before polling):
//      always safe (clobber of izin[t+1] is licensed only by our tag-(t+1)
//      publish, which still follows the pre-publish vmcnt(0) drain), and
//      the drain becomes free since the loads retire during poll+MFMA.
// ---------------------------------------------------------------------------
__global__ __launch_bounds__(512, 1) void gru_scan(
    const _Float16* __restrict__ Whc,   // [1024][512] f16
    const char* izb,                    // d_out bytes: blocked izin (aliases Hout)
    float* Hout,                        // d_out as f32 [t][b][j]
    unsigned int* hbuf32)               // [2][128][512] tagged u32
{
    __shared__ _Float16 hlds[2 * 16 * 512];   // 32 KB, XOR-swizzled (^(b&7)<<3)

    const int blk  = blockIdx.x;        // 0..31
    const int g    = blk & 7;
    const int slot = blk >> 3;          // 0..3
    const int tid  = threadIdx.x;
    const int wv   = tid >> 6;          // wave 0..7
    const int l    = tid & 63;
    const int lrow = l & 15, lk = l >> 4;
    const int jbase = slot * 128 + wv * 16;
    const int jq    = jbase + 4 * lk;            // lane's j quad base
    const int bg    = 16 * g + lrow;             // lane's global b (frag row)
    const int blk_s = 16 * g + 4 * slot + (wv >> 1);  // izin record index
    const int stage_b = tid >> 5;                // 0..15 (partner staging b)
    const int stage_jq = 4 * (tid & 31);         // 0..124 (partner staging j-quad)

    // ---- register-resident weights: rows jbase+lrow (z), 512+jbase+lrow (n)
    f16x8 wz[16], wn[16];
#pragma unroll
    for (int s = 0; s < 16; ++s) {
        wz[s] = *(const f16x8*)&Whc[(size_t)(jbase + lrow) * 512 + s * 32 + lk * 8];
        wn[s] = *(const f16x8*)&Whc[(size_t)(512 + jbase + lrow) * 512 + s * 32 + lk * 8];
    }

    // ---- seed own h_0 = 0 into hlds[0] (parity of step 0)
    *(unsigned long long*)&hlds[(lrow * 512 + jq) ^ ((lrow & 7) << 3)] = 0ull;

    // ---- izin[0] prefetch (plain u64 loads; gemm_proj wrote before launch)
    QZ pz, pn, npz, npn;
    {
        const char* rec = izb + ((size_t)0 * 128 + blk_s) * 2048 + l * 16 + (wv & 1) * 8;
        pz.q = *(const unsigned long long*)rec;
        pn.q = *(const unsigned long long*)(rec + 1024);
    }

    float hm[4] = {0.f, 0.f, 0.f, 0.f};   // h[bg][jq+r] master (f32)

    for (int t = 0; t < T_LEN; ++t) {
        const int par = (t + 1) & 1;           // parity holding h_t
        const int lp  = t & 1;                 // LDS buffer for h_t
        const unsigned long long tp =
            (unsigned long long)(unsigned)t | ((unsigned long long)(unsigned)t << 32);

        // ---- izin[t+1] loads FIRST (retire during poll+MFMA; see header)
        if (t + 1 < T_LEN) {
            const char* rec = izb + ((size_t)(t + 1) * 128 + blk_s) * 2048
                              + l * 16 + (wv & 1) * 8;
            npz.q = *(const unsigned long long*)rec;
            npn.q = *(const unsigned long long*)(rec + 1024);
        }
        __builtin_amdgcn_sched_barrier(0);

        // ---- partner tagged loads: 3 quads/thread (one per partner slot)
        const unsigned long long* hb64 =
            (const unsigned long long*)(hbuf32 + (size_t)par * 65536);
        unsigned long long q0[3], q1[3];
        int pix[3];
#pragma unroll
        for (int i = 0; i < 3; ++i) {
            const int s_i = (slot + 1 + i) & 3;
            const int u32i = (16 * g + stage_b) * 512 + s_i * 128 + stage_jq;
            pix[i] = u32i >> 1;
            q0[i] = __hip_atomic_load(hb64 + pix[i],     RLX, AGT);
            q1[i] = __hip_atomic_load(hb64 + pix[i] + 1, RLX, AGT);
        }
#pragma unroll
        for (int i = 0; i < 3; ++i) {
            while (true) {
                const unsigned long long x = (q0[i] ^ tp) | (q1[i] ^ tp);
                if (__all((x & 0x0000FFFF0000FFFFull) == 0)) break;
                q0[i] = __hip_atomic_load(hb64 + pix[i],     RLX, AGT);
                q1[i] = __hip_atomic_load(hb64 + pix[i] + 1, RLX, AGT);
            }
        }
        // ---- unpack (strip tags) + swizzled LDS stage
#pragma unroll
        for (int i = 0; i < 3; ++i) {
            const int s_i = (slot + 1 + i) & 3;
            const unsigned int w0 = ((unsigned int)(q0[i] >> 16)) & 0xFFFFu;
            const unsigned int w1 = (unsigned int)(q0[i] >> 48);
            const unsigned int w2 = ((unsigned int)(q1[i] >> 16)) & 0xFFFFu;
            const unsigned int w3 = (unsigned int)(q1[i] >> 48);
            const unsigned long long out =
                (unsigned long long)(w0 | (w1 << 16)) |
                ((unsigned long long)(w2 | (w3 << 16)) << 32);
            const int idx = (lp * 8192 + stage_b * 512 + s_i * 128 + stage_jq)
                            ^ ((stage_b & 7) << 3);
            *(unsigned long long*)&hlds[idx] = out;
        }

        __syncthreads();

        // ---- MFMA: 2 tiles (z, n) x 16 k-slices; B-frags from swizzled LDS
        f32x4 az = {0.f, 0.f, 0.f, 0.f}, an = {0.f, 0.f, 0.f, 0.f};
        const int hbase = lp * 8192 + lrow * 512;
        const int sw = (lrow & 7) << 3;
#pragma unroll
        for (int s = 0; s < 16; ++s) {
            const f16x8 hf = *(const f16x8*)&hlds[(hbase + s * 32 + lk * 8) ^ sw];
            az = __builtin_amdgcn_mfma_f32_16x16x32_f16(wz[s], hf, az, 0, 0, 0);
            an = __builtin_amdgcn_mfma_f32_16x16x32_f16(wn[s], hf, an, 0, 0, 0);
        }

        // ---- gates + state update (f32)
        PK4 own;
        f32x4 Hv;
#pragma unroll
        for (int r = 0; r < 4; ++r) {
            float zpre = az[r] + (float)pz.v[r];
            float npre = an[r] + (float)pn.v[r];
            zpre = fminf(fmaxf(zpre, -30.f), 30.f);
            const float z = 1.f / (1.f + __expf(-zpre));
            npre = fminf(fmaxf(npre, -15.f), 15.f);
            const float e2 = __expf(2.f * npre);
            const float n = (e2 - 1.f) / (e2 + 1.f);
            hm[r] = (1.f - z) * n + z * hm[r];
            Hv[r] = hm[r];
            own.h[r] = (_Float16)hm[r];
        }

        // ---- stage own h_{t+1} chunk for next step (LDS parity (t+1)&1)
        *(unsigned long long*)
            &hlds[(((t + 1) & 1) * 8192 + lrow * 512 + jq) ^ ((lrow & 7) << 3)] = own.q;

        if (t < T_LEN - 1) {
            // ---- drain izin[t+1] (long retired -> cheap), then publish
            asm volatile("s_waitcnt vmcnt(0)" ::: "memory");
            __builtin_amdgcn_sched_barrier(0);
            const unsigned long long tagp =
                (unsigned long long)(unsigned)(t + 1) |
                ((unsigned long long)(unsigned)(t + 1) << 32);
            const unsigned long long d0 =
                ((own.q & 0xFFFFull) << 16) |
                (((own.q >> 16) & 0xFFFFull) << 48) | tagp;
            const unsigned long long d1 =
                (((own.q >> 32) & 0xFFFFull) << 16) |
                (((own.q >> 48) & 0xFFFFull) << 48) | tagp;
            unsigned long long* hw = (unsigned long long*)
                (hbuf32 + (size_t)(t & 1) * 65536 + (size_t)bg * 512 + jq);
            __hip_atomic_store(hw,     d0, RLX, AGT);
            __hip_atomic_store(hw + 1, d1, RLX, AGT);
        }

        // ---- H[t] store (fire-and-forget; safe: all tags==t seen pre-barrier)
        *(f32x4*)&Hout[(size_t)t * 65536 + (size_t)bg * 512 + jq] = Hv;

        pz = npz; pn = npn;
    }
}

// ---------------------------------------------------------------------------
extern "C" void kernel_launch(void* const* d_in, const int* in_sizes, int n_in,
                              void* d_out, int out_size, void* d_ws, size_t ws_size,
                              hipStream_t stream) {
    (void)in_sizes; (void)n_in; (void)out_size; (void)ws_size;
    const float* seq  = (const float*)d_in[0];
    const float* W_iz = (const float*)d_in[1];
    const float* b_iz = (const float*)d_in[2];
    const float* W_in = (const float*)d_in[3];
    const float* b_in = (const float*)d_in[4];
    const float* W_hz = (const float*)d_in[5];
    const float* b_hz = (const float*)d_in[6];
    const float* W_hn = (const float*)d_in[7];
    const float* b_hn = (const float*)d_in[8];

    char* ws = (char*)d_ws;                                 // total use: ~2.6 MB
    _Float16*     Wci    = (_Float16*)(ws);                 // 1,048,576 B
    _Float16*     Whc    = (_Float16*)(ws + 1048576);       // 1,048,576 B
    float*        bc     = (float*)   (ws + 2097152);       //     4,096 B
    unsigned int* hbuf32 = (unsigned int*)(ws + 2101248);   //   524,288 B tagged

    prep_misc<<<644, 256, 0, stream>>>(W_iz, W_in, W_hz, W_hn,
                                       b_iz, b_in, b_hz, b_hn,
                                       Wci, Whc, bc, hbuf32);
    gemm_proj<<<dim3(512, 8), 256, 0, stream>>>(seq, Wci, bc, (_Float16*)d_out);
    gru_scan<<<32, 512, 0, stream>>>(Whc, (const char*)d_out, (float*)d_out, hbuf32);
}

// Round 11
// 1914.755 us; speedup vs baseline: 1.8916x; 1.0532x over previous
//
#include <hip/hip_runtime.h>
#include <stdint.h>

typedef _Float16 f16x8 __attribute__((ext_vector_type(8)));
typedef _Float16 f16x4 __attribute__((ext_vector_type(4)));
typedef float    f32x4 __attribute__((ext_vector_type(4)));
typedef unsigned int u32x4v __attribute__((ext_vector_type(4)));

#define T_LEN 512
#define RLX   __ATOMIC_RELAXED
#define AGT   __HIP_MEMORY_SCOPE_AGENT

union PK4 { _Float16 h[4]; unsigned long long q; };
union QZ  { unsigned long long q; f16x4 v; };

// ---------------------------------------------------------------------------
// async global->LDS (16B/lane). LDS dest = wave-uniform base + lane*16.
// GLOBAL SOURCE IS PER-LANE.
// ---------------------------------------------------------------------------
__device__ __forceinline__ void gload_lds16(const void* gsrc, void* ldsdst) {
    auto g = (const __attribute__((address_space(1))) void*)(reinterpret_cast<uintptr_t>(gsrc));
    auto s = (__attribute__((address_space(3))) void*)(reinterpret_cast<uintptr_t>(ldsdst));
    __builtin_amdgcn_global_load_lds(g, s, 16, 0, 0);
}

// ---------------------------------------------------------------------------
// prep: f16 weights (Wci=[W_iz;W_in], Whc=[W_hz;W_hn]), bc=b_i+b_h,
// zero tagged hbuf (tag 0 = step-0 seed, h_0=0). Runs every launch (replays).
// ---------------------------------------------------------------------------
__global__ __launch_bounds__(256) void prep_misc(
    const float* __restrict__ W_iz, const float* __restrict__ W_in,
    const float* __restrict__ W_hz, const float* __restrict__ W_hn,
    const float* __restrict__ b_iz, const float* __restrict__ b_in,
    const float* __restrict__ b_hz, const float* __restrict__ b_hn,
    _Float16* __restrict__ Wci, _Float16* __restrict__ Whc,
    float* __restrict__ bc, unsigned int* __restrict__ hbuf32)
{
    const int tid = blockIdx.x * 256 + threadIdx.x;
    if (tid < 131072) {                      // 2 * 1024*512/8 weight vec units
        const bool is_h = tid >= 65536;
        const int u = tid & 65535;
        const int e = u * 8;
        const int row = e >> 9;
        const int k = e & 511;
        const float* s;
        if (!is_h) s = (row < 512) ? (W_iz + (size_t)row * 512 + k)
                                   : (W_in + (size_t)(row - 512) * 512 + k);
        else       s = (row < 512) ? (W_hz + (size_t)row * 512 + k)
                                   : (W_hn + (size_t)(row - 512) * 512 + k);
        f32x4 a = *(const f32x4*)s;
        f32x4 b = *(const f32x4*)(s + 4);
        f16x8 o;
        o[0] = (_Float16)a[0]; o[1] = (_Float16)a[1];
        o[2] = (_Float16)a[2]; o[3] = (_Float16)a[3];
        o[4] = (_Float16)b[0]; o[5] = (_Float16)b[1];
        o[6] = (_Float16)b[2]; o[7] = (_Float16)b[3];
        _Float16* d = is_h ? Whc : Wci;
        *(f16x8*)(d + e) = o;
    } else if (tid < 132096) {               // 1024 combined biases
        const int j2 = tid - 131072;
        bc[j2] = (j2 < 512) ? (b_iz[j2] + b_hz[j2]) : (b_in[j2 - 512] + b_hn[j2 - 512]);
    } else if (tid < 164864) {               // zero tagged hbuf: 131072 u32 / 4
        const int u = tid - 132096;
        u32x4v z = {0u, 0u, 0u, 0u};
        *(u32x4v*)(hbuf32 + (size_t)u * 4) = z;
    }
}

// ---------------------------------------------------------------------------
// Phase 1: input projections -> BLOCKED izin records (f16, into d_out):
//   record (t, blk_s) = 2KB at byte (t*128+blk_s)*2048: [z 1KB][n 1KB];
//   in-gate: lane l (64) x 16B = [quad j0+4*(l>>4), quad j0+16+4*(l>>4)],
//   b = 16*(blk_s>>4) + (l&15), j0 = 32*(blk_s&15).
// (UNCHANGED — verified rounds 4/6/8/9/10.)
// ---------------------------------------------------------------------------
__global__ __launch_bounds__(256) void gemm_proj(
    const float* __restrict__ A,      // seq [65536][512] f32 (row = t*128+b)
    const _Float16* __restrict__ Bw,  // Wci [1024][512] f16
    const float* __restrict__ bc,     // [1024] f32
    _Float16* Co)                     // blocked izin (= d_out as f16)
{
    __shared__ _Float16 As[128 * 40];   // padded stride 40 f16
    __shared__ _Float16 Bs[128 * 32];   // linear (global_load_lds target)

    const int mt = blockIdx.x;          // = t
    const int nt = blockIdx.y;          // 0..7 (0-3: z gate, 4-7: n gate)
    const int m0 = mt * 128, n0 = nt * 128;
    const int tid = threadIdx.x;
    const int w = tid >> 6, l = tid & 63;
    const int wr = w >> 1, wc = w & 1;
    const int lrow = l & 15, lk = l >> 4;

    f32x4 acc[4][4] = {};

    const int arow = tid >> 1;
    const int acol = (tid & 1) * 16;

    for (int kt = 0; kt < 16; ++kt) {
        const int k0 = kt * 32;
        if (kt) __syncthreads();
        const float* as = A + (size_t)(m0 + arow) * 512 + k0 + acol;
        f32x4 a0 = *(const f32x4*)as;
        f32x4 a1 = *(const f32x4*)(as + 4);
        f32x4 a2 = *(const f32x4*)(as + 8);
        f32x4 a3 = *(const f32x4*)(as + 12);
        f16x8 h0, h1;
#pragma unroll
        for (int e = 0; e < 4; ++e) {
            h0[e] = (_Float16)a0[e]; h0[4 + e] = (_Float16)a1[e];
            h1[e] = (_Float16)a2[e]; h1[4 + e] = (_Float16)a3[e];
        }
        *(f16x8*)&As[arow * 40 + acol] = h0;
        *(f16x8*)&As[arow * 40 + acol + 8] = h1;
#pragma unroll
        for (int i = 0; i < 2; ++i) {
            const int chunk = w * 2 + i;
            const _Float16* gsrc =
                Bw + (size_t)(n0 + chunk * 16 + (l >> 2)) * 512 + k0 + (l & 3) * 8;
            gload_lds16(gsrc, &Bs[chunk * 512]);
        }
        __syncthreads();
        f16x8 af[4], bf[4];
#pragma unroll
        for (int i = 0; i < 4; ++i) {
            af[i] = *(const f16x8*)&As[(wr * 64 + i * 16 + lrow) * 40 + lk * 8];
            bf[i] = *(const f16x8*)&Bs[(wc * 64 + i * 16 + lrow) * 32 + lk * 8];
        }
#pragma unroll
        for (int mi = 0; mi < 4; ++mi)
#pragma unroll
            for (int ni = 0; ni < 4; ++ni)
                acc[mi][ni] = __builtin_amdgcn_mfma_f32_16x16x32_f16(
                    bf[ni], af[mi], acc[mi][ni], 0, 0, 0);
    }
    // epilogue: bias + cvt f16 + blocked store
    const int gate = nt >> 2;
#pragma unroll
    for (int mi = 0; mi < 4; ++mi) {
#pragma unroll
        for (int p = 0; p < 2; ++p) {
            const int j2q0 = n0 + wc * 64 + p * 32 + 4 * lk;
            const f32x4 b0 = *(const f32x4*)&bc[j2q0];
            const f32x4 b1 = *(const f32x4*)&bc[j2q0 + 16];
            f16x8 o;
#pragma unroll
            for (int r = 0; r < 4; ++r) {
                o[r]     = (_Float16)(acc[mi][2 * p][r]     + b0[r]);
                o[4 + r] = (_Float16)(acc[mi][2 * p + 1][r] + b1[r]);
            }
            const int blk_s = (wr * 4 + mi) * 16 + (nt & 3) * 4 + wc * 2 + p;
            _Float16* dst = Co + ((((size_t)mt * 128 + blk_s) * 2 + gate) * 512) + l * 8;
            *(f16x8*)dst = o;
        }
    }
}

// ---------------------------------------------------------------------------
// Phase 2: persistent scan — 32 WGs x 8 waves (512 thr).
// Structure of rounds 9/10 with three fixes:
//  (a) weight fragments PINNED in VGPRs via asm "+v" (rounds 9/10: the
//      allocator demoted them -> per-step 32KB/wave scratch reloads inside
//      the MFMA loop; VGPR_Count was 96, should now be ~200).
//  (b) FUSED retry loop: reload ALL three partners each retry iteration
//      (round 10's sequential per-partner whiles stacked up to 3 LLC RTs).
//  (c) izin[t+1] loads issued AFTER the poll (round 9 position): the first
//      tag check no longer waits izin's ~900cy HBM latency (in-order vmcnt);
//      izin retires under the MFMA phase, pre-publish vmcnt(0) stays free.
// ---------------------------------------------------------------------------
__global__ __launch_bounds__(512, 1) void gru_scan(
    const _Float16* __restrict__ Whc,   // [1024][512] f16
    const char* izb,                    // d_out bytes: blocked izin (aliases Hout)
    float* Hout,                        // d_out as f32 [t][b][j]
    unsigned int* hbuf32)               // [2][128][512] tagged u32
{
    __shared__ _Float16 hlds[2 * 16 * 512];   // 32 KB, XOR-swizzled (^(b&7)<<3)

    const int blk  = blockIdx.x;        // 0..31
    const int g    = blk & 7;
    const int slot = blk >> 3;          // 0..3
    const int tid  = threadIdx.x;
    const int wv   = tid >> 6;          // wave 0..7
    const int l    = tid & 63;
    const int lrow = l & 15, lk = l >> 4;
    const int jbase = slot * 128 + wv * 16;
    const int jq    = jbase + 4 * lk;            // lane's j quad base
    const int bg    = 16 * g + lrow;             // lane's global b (frag row)
    const int blk_s = 16 * g + 4 * slot + (wv >> 1);  // izin record index
    const int stage_b = tid >> 5;                // 0..15 (partner staging b)
    const int stage_jq = 4 * (tid & 31);         // 0..124 (partner staging j-quad)

    // ---- register-resident weights: rows jbase+lrow (z), 512+jbase+lrow (n)
    f16x8 wz[16], wn[16];
#pragma unroll
    for (int s = 0; s < 16; ++s) {
        wz[s] = *(const f16x8*)&Whc[(size_t)(jbase + lrow) * 512 + s * 32 + lk * 8];
        wn[s] = *(const f16x8*)&Whc[(size_t)(512 + jbase + lrow) * 512 + s * 32 + lk * 8];
    }
    // PIN in VGPRs: values become asm-defined register operands, so the
    // allocator cannot demote them to scratch / reload them in the loop.
#pragma unroll
    for (int s = 0; s < 16; ++s) {
        asm volatile("" : "+v"(wz[s]));
        asm volatile("" : "+v"(wn[s]));
    }

    // ---- seed own h_0 = 0 into hlds[0] (parity of step 0)
    *(unsigned long long*)&hlds[(lrow * 512 + jq) ^ ((lrow & 7) << 3)] = 0ull;

    // ---- izin[0] prefetch (plain u64 loads; gemm_proj wrote before launch)
    QZ pz, pn, npz, npn;
    {
        const char* rec = izb + ((size_t)0 * 128 + blk_s) * 2048 + l * 16 + (wv & 1) * 8;
        pz.q = *(const unsigned long long*)rec;
        pn.q = *(const unsigned long long*)(rec + 1024);
    }

    float hm[4] = {0.f, 0.f, 0.f, 0.f};   // h[bg][jq+r] master (f32)

    for (int t = 0; t < T_LEN; ++t) {
        const int par = (t + 1) & 1;           // parity holding h_t
        const int lp  = t & 1;                 // LDS buffer for h_t
        const unsigned long long tp =
            (unsigned long long)(unsigned)t | ((unsigned long long)(unsigned)t << 32);

        // ---- partner tagged loads: 3 quads/thread (one per partner slot)
        const unsigned long long* hb64 =
            (const unsigned long long*)(hbuf32 + (size_t)par * 65536);
        unsigned long long q0[3], q1[3];
        int pix[3];
#pragma unroll
        for (int i = 0; i < 3; ++i) {
            const int s_i = (slot + 1 + i) & 3;
            const int u32i = (16 * g + stage_b) * 512 + s_i * 128 + stage_jq;
            pix[i] = u32i >> 1;
            q0[i] = __hip_atomic_load(hb64 + pix[i],     RLX, AGT);
            q1[i] = __hip_atomic_load(hb64 + pix[i] + 1, RLX, AGT);
        }
        // ---- FUSED retry: one iteration = reload ALL partners (overlapped)
        while (true) {
            unsigned long long x = 0;
#pragma unroll
            for (int i = 0; i < 3; ++i)
                x |= (q0[i] ^ tp) | (q1[i] ^ tp);
            if (__all((x & 0x0000FFFF0000FFFFull) == 0)) break;
#pragma unroll
            for (int i = 0; i < 3; ++i) {
                q0[i] = __hip_atomic_load(hb64 + pix[i],     RLX, AGT);
                q1[i] = __hip_atomic_load(hb64 + pix[i] + 1, RLX, AGT);
            }
        }

        // ---- izin[t+1] loads now (retire under MFMA; see header)
        if (t + 1 < T_LEN) {
            const char* rec = izb + ((size_t)(t + 1) * 128 + blk_s) * 2048
                              + l * 16 + (wv & 1) * 8;
            npz.q = *(const unsigned long long*)rec;
            npn.q = *(const unsigned long long*)(rec + 1024);
        }
        __builtin_amdgcn_sched_barrier(0);

        // ---- unpack (strip tags) + swizzled LDS stage
#pragma unroll
        for (int i = 0; i < 3; ++i) {
            const int s_i = (slot + 1 + i) & 3;
            const unsigned int w0 = ((unsigned int)(q0[i] >> 16)) & 0xFFFFu;
            const unsigned int w1 = (unsigned int)(q0[i] >> 48);
            const unsigned int w2 = ((unsigned int)(q1[i] >> 16)) & 0xFFFFu;
            const unsigned int w3 = (unsigned int)(q1[i] >> 48);
            const unsigned long long out =
                (unsigned long long)(w0 | (w1 << 16)) |
                ((unsigned long long)(w2 | (w3 << 16)) << 32);
            const int idx = (lp * 8192 + stage_b * 512 + s_i * 128 + stage_jq)
                            ^ ((stage_b & 7) << 3);
            *(unsigned long long*)&hlds[idx] = out;
        }

        __syncthreads();

        // ---- MFMA: 2 tiles (z, n) x 16 k-slices; B-frags from swizzled LDS
        f32x4 az = {0.f, 0.f, 0.f, 0.f}, an = {0.f, 0.f, 0.f, 0.f};
        const int hbase = lp * 8192 + lrow * 512;
        const int sw = (lrow & 7) << 3;
#pragma unroll
        for (int s = 0; s < 16; ++s) {
            const f16x8 hf = *(const f16x8*)&hlds[(hbase + s * 32 + lk * 8) ^ sw];
            az = __builtin_amdgcn_mfma_f32_16x16x32_f16(wz[s], hf, az, 0, 0, 0);
            an = __builtin_amdgcn_mfma_f32_16x16x32_f16(wn[s], hf, an, 0, 0, 0);
        }

        // ---- gates + state update (f32)
        PK4 own;
        f32x4 Hv;
#pragma unroll
        for (int r = 0; r < 4; ++r) {
            float zpre = az[r] + (float)pz.v[r];
            float npre = an[r] + (float)pn.v[r];
            zpre = fminf(fmaxf(zpre, -30.f), 30.f);
            const float z = 1.f / (1.f + __expf(-zpre));
            npre = fminf(fmaxf(npre, -15.f), 15.f);
            const float e2 = __expf(2.f * npre);
            const float n = (e2 - 1.f) / (e2 + 1.f);
            hm[r] = (1.f - z) * n + z * hm[r];
            Hv[r] = hm[r];
            own.h[r] = (_Float16)hm[r];
        }

        // ---- stage own h_{t+1} chunk for next step (LDS parity (t+1)&1)
        *(unsigned long long*)
            &hlds[(((t + 1) & 1) * 8192 + lrow * 512 + jq) ^ ((lrow & 7) << 3)] = own.q;

        if (t < T_LEN - 1) {
            // ---- drain izin[t+1] (long retired -> cheap), then publish
            asm volatile("s_waitcnt vmcnt(0)" ::: "memory");
            __builtin_amdgcn_sched_barrier(0);
            const unsigned long long tagp =
                (unsigned long long)(unsigned)(t + 1) |
                ((unsigned long long)(unsigned)(t + 1) << 32);
            const unsigned long long d0 =
                ((own.q & 0xFFFFull) << 16) |
                (((own.q >> 16) & 0xFFFFull) << 48) | tagp;
            const unsigned long long d1 =
                (((own.q >> 32) & 0xFFFFull) << 16) |
                (((own.q >> 48) & 0xFFFFull) << 48) | tagp;
            unsigned long long* hw = (unsigned long long*)
                (hbuf32 + (size_t)(t & 1) * 65536 + (size_t)bg * 512 + jq);
            __hip_atomic_store(hw,     d0, RLX, AGT);
            __hip_atomic_store(hw + 1, d1, RLX, AGT);
        }

        // ---- H[t] store (fire-and-forget; safe: all tags==t seen pre-barrier)
        *(f32x4*)&Hout[(size_t)t * 65536 + (size_t)bg * 512 + jq] = Hv;

        pz = npz; pn = npn;
    }
}

// ---------------------------------------------------------------------------
extern "C" void kernel_launch(void* const* d_in, const int* in_sizes, int n_in,
                              void* d_out, int out_size, void* d_ws, size_t ws_size,
                              hipStream_t stream) {
    (void)in_sizes; (void)n_in; (void)out_size; (void)ws_size;
    const float* seq  = (const float*)d_in[0];
    const float* W_iz = (const float*)d_in[1];
    const float* b_iz = (const float*)d_in[2];
    const float* W_in = (const float*)d_in[3];
    const float* b_in = (const float*)d_in[4];
    const float* W_hz = (const float*)d_in[5];
    const float* b_hz = (const float*)d_in[6];
    const float* W_hn = (const float*)d_in[7];
    const float* b_hn = (const float*)d_in[8];

    char* ws = (char*)d_ws;                                 // total use: ~2.6 MB
    _Float16*     Wci    = (_Float16*)(ws);                 // 1,048,576 B
    _Float16*     Whc    = (_Float16*)(ws + 1048576);       // 1,048,576 B
    float*        bc     = (float*)   (ws + 2097152);       //     4,096 B
    unsigned int* hbuf32 = (unsigned int*)(ws + 2101248);   //   524,288 B tagged

    prep_misc<<<644, 256, 0, stream>>>(W_iz, W_in, W_hz, W_hn,
                                       b_iz, b_in, b_hz, b_hn,
                                       Wci, Whc, bc, hbuf32);
    gemm_proj<<<dim3(512, 8), 256, 0, stream>>>(seq, Wci, bc, (_Float16*)d_out);
    gru_scan<<<32, 512, 0, stream>>>(Whc, (const char*)d_out, (float*)d_out, hbuf32);
}

// Round 12
// 1826.632 us; speedup vs baseline: 1.9829x; 1.0482x over previous
//
#include <hip/hip_runtime.h>
#include <stdint.h>

typedef _Float16 f16x8 __attribute__((ext_vector_type(8)));
typedef _Float16 f16x4 __attribute__((ext_vector_type(4)));
typedef float    f32x4 __attribute__((ext_vector_type(4)));
typedef unsigned int u32x4v __attribute__((ext_vector_type(4)));

#define T_LEN 512
#define RLX   __ATOMIC_RELAXED
#define AGT   __HIP_MEMORY_SCOPE_AGENT

union PK4 { _Float16 h[4]; unsigned long long q; };
union QZ  { unsigned long long q; f16x4 v; };

// ---------------------------------------------------------------------------
// async global->LDS (16B/lane). LDS dest = wave-uniform base + lane*16.
// GLOBAL SOURCE IS PER-LANE.
// ---------------------------------------------------------------------------
__device__ __forceinline__ void gload_lds16(const void* gsrc, void* ldsdst) {
    auto g = (const __attribute__((address_space(1))) void*)(reinterpret_cast<uintptr_t>(gsrc));
    auto s = (__attribute__((address_space(3))) void*)(reinterpret_cast<uintptr_t>(ldsdst));
    __builtin_amdgcn_global_load_lds(g, s, 16, 0, 0);
}

// ---------------------------------------------------------------------------
// prep: f16 weights (Wci=[W_iz;W_in], Whc=[W_hz;W_hn]), bc=b_i+b_h,
// zero tagged hbuf (tag 0 = step-0 seed, h_0=0). Runs every launch (replays).
// ---------------------------------------------------------------------------
__global__ __launch_bounds__(256) void prep_misc(
    const float* __restrict__ W_iz, const float* __restrict__ W_in,
    const float* __restrict__ W_hz, const float* __restrict__ W_hn,
    const float* __restrict__ b_iz, const float* __restrict__ b_in,
    const float* __restrict__ b_hz, const float* __restrict__ b_hn,
    _Float16* __restrict__ Wci, _Float16* __restrict__ Whc,
    float* __restrict__ bc, unsigned int* __restrict__ hbuf32)
{
    const int tid = blockIdx.x * 256 + threadIdx.x;
    if (tid < 131072) {                      // 2 * 1024*512/8 weight vec units
        const bool is_h = tid >= 65536;
        const int u = tid & 65535;
        const int e = u * 8;
        const int row = e >> 9;
        const int k = e & 511;
        const float* s;
        if (!is_h) s = (row < 512) ? (W_iz + (size_t)row * 512 + k)
                                   : (W_in + (size_t)(row - 512) * 512 + k);
        else       s = (row < 512) ? (W_hz + (size_t)row * 512 + k)
                                   : (W_hn + (size_t)(row - 512) * 512 + k);
        f32x4 a = *(const f32x4*)s;
        f32x4 b = *(const f32x4*)(s + 4);
        f16x8 o;
        o[0] = (_Float16)a[0]; o[1] = (_Float16)a[1];
        o[2] = (_Float16)a[2]; o[3] = (_Float16)a[3];
        o[4] = (_Float16)b[0]; o[5] = (_Float16)b[1];
        o[6] = (_Float16)b[2]; o[7] = (_Float16)b[3];
        _Float16* d = is_h ? Whc : Wci;
        *(f16x8*)(d + e) = o;
    } else if (tid < 132096) {               // 1024 combined biases
        const int j2 = tid - 131072;
        bc[j2] = (j2 < 512) ? (b_iz[j2] + b_hz[j2]) : (b_in[j2 - 512] + b_hn[j2 - 512]);
    } else if (tid < 164864) {               // zero tagged hbuf: 131072 u32 / 4
        const int u = tid - 132096;
        u32x4v z = {0u, 0u, 0u, 0u};
        *(u32x4v*)(hbuf32 + (size_t)u * 4) = z;
    }
}

// ---------------------------------------------------------------------------
// Phase 1: input projections -> BLOCKED izin records (f16, into d_out):
//   record (t, blk_s) = 2KB at byte (t*128+blk_s)*2048: [z 1KB][n 1KB];
//   in-gate: lane l (64) x 16B = [quad j0+4*(l>>4), quad j0+16+4*(l>>4)],
//   b = 16*(blk_s>>4) + (l&15), j0 = 32*(blk_s&15).
// (UNCHANGED — verified rounds 4/6/8/9/10/11.)
// ---------------------------------------------------------------------------
__global__ __launch_bounds__(256) void gemm_proj(
    const float* __restrict__ A,      // seq [65536][512] f32 (row = t*128+b)
    const _Float16* __restrict__ Bw,  // Wci [1024][512] f16
    const float* __restrict__ bc,     // [1024] f32
    _Float16* Co)                     // blocked izin (= d_out as f16)
{
    __shared__ _Float16 As[128 * 40];   // padded stride 40 f16
    __shared__ _Float16 Bs[128 * 32];   // linear (global_load_lds target)

    const int mt = blockIdx.x;          // = t
    const int nt = blockIdx.y;          // 0..7 (0-3: z gate, 4-7: n gate)
    const int m0 = mt * 128, n0 = nt * 128;
    const int tid = threadIdx.x;
    const int w = tid >> 6, l = tid & 63;
    const int wr = w >> 1, wc = w & 1;
    const int lrow = l & 15, lk = l >> 4;

    f32x4 acc[4][4] = {};

    const int arow = tid >> 1;
    const int acol = (tid & 1) * 16;

    for (int kt = 0; kt < 16; ++kt) {
        const int k0 = kt * 32;
        if (kt) __syncthreads();
        const float* as = A + (size_t)(m0 + arow) * 512 + k0 + acol;
        f32x4 a0 = *(const f32x4*)as;
        f32x4 a1 = *(const f32x4*)(as + 4);
        f32x4 a2 = *(const f32x4*)(as + 8);
        f32x4 a3 = *(const f32x4*)(as + 12);
        f16x8 h0, h1;
#pragma unroll
        for (int e = 0; e < 4; ++e) {
            h0[e] = (_Float16)a0[e]; h0[4 + e] = (_Float16)a1[e];
            h1[e] = (_Float16)a2[e]; h1[4 + e] = (_Float16)a3[e];
        }
        *(f16x8*)&As[arow * 40 + acol] = h0;
        *(f16x8*)&As[arow * 40 + acol + 8] = h1;
#pragma unroll
        for (int i = 0; i < 2; ++i) {
            const int chunk = w * 2 + i;
            const _Float16* gsrc =
                Bw + (size_t)(n0 + chunk * 16 + (l >> 2)) * 512 + k0 + (l & 3) * 8;
            gload_lds16(gsrc, &Bs[chunk * 512]);
        }
        __syncthreads();
        f16x8 af[4], bf[4];
#pragma unroll
        for (int i = 0; i < 4; ++i) {
            af[i] = *(const f16x8*)&As[(wr * 64 + i * 16 + lrow) * 40 + lk * 8];
            bf[i] = *(const f16x8*)&Bs[(wc * 64 + i * 16 + lrow) * 32 + lk * 8];
        }
#pragma unroll
        for (int mi = 0; mi < 4; ++mi)
#pragma unroll
            for (int ni = 0; ni < 4; ++ni)
                acc[mi][ni] = __builtin_amdgcn_mfma_f32_16x16x32_f16(
                    bf[ni], af[mi], acc[mi][ni], 0, 0, 0);
    }
    // epilogue: bias + cvt f16 + blocked store
    const int gate = nt >> 2;
#pragma unroll
    for (int mi = 0; mi < 4; ++mi) {
#pragma unroll
        for (int p = 0; p < 2; ++p) {
            const int j2q0 = n0 + wc * 64 + p * 32 + 4 * lk;
            const f32x4 b0 = *(const f32x4*)&bc[j2q0];
            const f32x4 b1 = *(const f32x4*)&bc[j2q0 + 16];
            f16x8 o;
#pragma unroll
            for (int r = 0; r < 4; ++r) {
                o[r]     = (_Float16)(acc[mi][2 * p][r]     + b0[r]);
                o[4 + r] = (_Float16)(acc[mi][2 * p + 1][r] + b1[r]);
            }
            const int blk_s = (wr * 4 + mi) * 16 + (nt & 3) * 4 + wc * 2 + p;
            _Float16* dst = Co + ((((size_t)mt * 128 + blk_s) * 2 + gate) * 512) + l * 8;
            *(f16x8*)dst = o;
        }
    }
}

// ---------------------------------------------------------------------------
// Phase 2: persistent scan — 32 WGs x 8 waves (512 thr).
// Round 11 structure with two fixes:
//  (a) IN-LOOP asm "+v" pins on every weight fragment: rounds 9-11 showed
//      VGPR_Count=96 — the compiler REMATERIALIZES weights from Whc (const)
//      inside the MFMA loop (L2 reloads, 32KB/wave/step). An asm that may
//      modify the register each iteration makes remat incorrect -> forces
//      true residency. Expect VGPR_Count ~200.
//  (b) izin prefetch depth 2 (even/odd reg sets, t-loop unrolled x2; refill
//      AFTER the gates consume the set) + pre-publish wait vmcnt(2): only
//      needs izin[t+1] (issued a full step ago) retired, so the publish is
//      never delayed by in-flight HBM izin loads.
// ---------------------------------------------------------------------------
__global__ __launch_bounds__(512, 1) void gru_scan(
    const _Float16* __restrict__ Whc,   // [1024][512] f16
    const char* izb,                    // d_out bytes: blocked izin (aliases Hout)
    float* Hout,                        // d_out as f32 [t][b][j]
    unsigned int* hbuf32)               // [2][128][512] tagged u32
{
    __shared__ _Float16 hlds[2 * 16 * 512];   // 32 KB, XOR-swizzled (^(b&7)<<3)

    const int blk  = blockIdx.x;        // 0..31
    const int g    = blk & 7;
    const int slot = blk >> 3;          // 0..3
    const int tid  = threadIdx.x;
    const int wv   = tid >> 6;          // wave 0..7
    const int l    = tid & 63;
    const int lrow = l & 15, lk = l >> 4;
    const int jbase = slot * 128 + wv * 16;
    const int jq    = jbase + 4 * lk;            // lane's j quad base
    const int bg    = 16 * g + lrow;             // lane's global b (frag row)
    const int blk_s = 16 * g + 4 * slot + (wv >> 1);  // izin record index
    const int stage_b = tid >> 5;                // 0..15 (partner staging b)
    const int stage_jq = 4 * (tid & 31);         // 0..124 (partner staging j-quad)

    // ---- weights: loaded once; in-loop pins (below) force register residency
    f16x8 wz[16], wn[16];
#pragma unroll
    for (int s = 0; s < 16; ++s) {
        wz[s] = *(const f16x8*)&Whc[(size_t)(jbase + lrow) * 512 + s * 32 + lk * 8];
        wn[s] = *(const f16x8*)&Whc[(size_t)(512 + jbase + lrow) * 512 + s * 32 + lk * 8];
    }

    // ---- seed own h_0 = 0 into hlds[0] (parity of step 0)
    *(unsigned long long*)&hlds[(lrow * 512 + jq) ^ ((lrow & 7) << 3)] = 0ull;

    // ---- izin prefetch depth 2: set E = izin[0], set O = izin[1]
    QZ ez, en, oz, on;
    {
        const char* r0 = izb + ((size_t)0 * 128 + blk_s) * 2048 + l * 16 + (wv & 1) * 8;
        ez.q = *(const unsigned long long*)r0;
        en.q = *(const unsigned long long*)(r0 + 1024);
        const char* r1 = izb + ((size_t)1 * 128 + blk_s) * 2048 + l * 16 + (wv & 1) * 8;
        oz.q = *(const unsigned long long*)r1;
        on.q = *(const unsigned long long*)(r1 + 1024);
    }

    float hm[4] = {0.f, 0.f, 0.f, 0.f};   // h[bg][jq+r] master (f32)

    const unsigned long long* hb64base = (const unsigned long long*)hbuf32;

    // ---------------- one scan step (consumes cz/cn, refills with izin[t+2])
    auto step = [&](int t, QZ& cz, QZ& cn) {
        const int par = (t + 1) & 1;           // parity holding h_t
        const int lp  = t & 1;                 // LDS buffer for h_t
        const unsigned long long tp =
            (unsigned long long)(unsigned)t | ((unsigned long long)(unsigned)t << 32);

        // ---- partner tagged loads: 3 quads/thread (one per partner slot)
        const unsigned long long* hb64 = hb64base + (size_t)par * 32768;
        unsigned long long q0[3], q1[3];
        int pix[3];
#pragma unroll
        for (int i = 0; i < 3; ++i) {
            const int s_i = (slot + 1 + i) & 3;
            const int u32i = (16 * g + stage_b) * 512 + s_i * 128 + stage_jq;
            pix[i] = u32i >> 1;
            q0[i] = __hip_atomic_load(hb64 + pix[i],     RLX, AGT);
            q1[i] = __hip_atomic_load(hb64 + pix[i] + 1, RLX, AGT);
        }
        // ---- FUSED retry: one iteration = reload ALL partners (overlapped)
        while (true) {
            unsigned long long x = 0;
#pragma unroll
            for (int i = 0; i < 3; ++i)
                x |= (q0[i] ^ tp) | (q1[i] ^ tp);
            if (__all((x & 0x0000FFFF0000FFFFull) == 0)) break;
#pragma unroll
            for (int i = 0; i < 3; ++i) {
                q0[i] = __hip_atomic_load(hb64 + pix[i],     RLX, AGT);
                q1[i] = __hip_atomic_load(hb64 + pix[i] + 1, RLX, AGT);
            }
        }

        // ---- unpack (strip tags) + swizzled LDS stage
#pragma unroll
        for (int i = 0; i < 3; ++i) {
            const int s_i = (slot + 1 + i) & 3;
            const unsigned int w0 = ((unsigned int)(q0[i] >> 16)) & 0xFFFFu;
            const unsigned int w1 = (unsigned int)(q0[i] >> 48);
            const unsigned int w2 = ((unsigned int)(q1[i] >> 16)) & 0xFFFFu;
            const unsigned int w3 = (unsigned int)(q1[i] >> 48);
            const unsigned long long out =
                (unsigned long long)(w0 | (w1 << 16)) |
                ((unsigned long long)(w2 | (w3 << 16)) << 32);
            const int idx = (lp * 8192 + stage_b * 512 + s_i * 128 + stage_jq)
                            ^ ((stage_b & 7) << 3);
            *(unsigned long long*)&hlds[idx] = out;
        }

        __syncthreads();

        // ---- MFMA: 2 tiles (z, n) x 16 k-slices; weights PINNED per use
        f32x4 az = {0.f, 0.f, 0.f, 0.f}, an = {0.f, 0.f, 0.f, 0.f};
        const int hbase = lp * 8192 + lrow * 512;
        const int sw = (lrow & 7) << 3;
#pragma unroll
        for (int s = 0; s < 16; ++s) {
            asm volatile("" : "+v"(wz[s]), "+v"(wn[s]));   // defeat remat
            const f16x8 hf = *(const f16x8*)&hlds[(hbase + s * 32 + lk * 8) ^ sw];
            az = __builtin_amdgcn_mfma_f32_16x16x32_f16(wz[s], hf, az, 0, 0, 0);
            an = __builtin_amdgcn_mfma_f32_16x16x32_f16(wn[s], hf, an, 0, 0, 0);
        }

        // ---- gates + state update (f32); consumes cz/cn
        PK4 own;
        f32x4 Hv;
#pragma unroll
        for (int r = 0; r < 4; ++r) {
            float zpre = az[r] + (float)cz.v[r];
            float npre = an[r] + (float)cn.v[r];
            zpre = fminf(fmaxf(zpre, -30.f), 30.f);
            const float z = 1.f / (1.f + __expf(-zpre));
            npre = fminf(fmaxf(npre, -15.f), 15.f);
            const float e2 = __expf(2.f * npre);
            const float n = (e2 - 1.f) / (e2 + 1.f);
            hm[r] = (1.f - z) * n + z * hm[r];
            Hv[r] = hm[r];
            own.h[r] = (_Float16)hm[r];
        }

        // ---- refill this set with izin[t+2] (retires over the next ~2 steps)
        if (t + 2 < T_LEN) {
            const char* rec = izb + ((size_t)(t + 2) * 128 + blk_s) * 2048
                              + l * 16 + (wv & 1) * 8;
            cz.q = *(const unsigned long long*)rec;
            cn.q = *(const unsigned long long*)(rec + 1024);
        }
        __builtin_amdgcn_sched_barrier(0);

        // ---- stage own h_{t+1} chunk for next step (LDS parity (t+1)&1)
        *(unsigned long long*)
            &hlds[(((t + 1) & 1) * 8192 + lrow * 512 + jq) ^ ((lrow & 7) << 3)] = own.q;

        if (t < T_LEN - 1) {
            // counted drain: only needs izin[t+1] (a full step old) retired;
            // leaves the 2 izin[t+2] loads in flight.
            if (t + 2 < T_LEN) {
                asm volatile("s_waitcnt vmcnt(2)" ::: "memory");
            } else {
                asm volatile("s_waitcnt vmcnt(0)" ::: "memory");
            }
            __builtin_amdgcn_sched_barrier(0);
            const unsigned long long tagp =
                (unsigned long long)(unsigned)(t + 1) |
                ((unsigned long long)(unsigned)(t + 1) << 32);
            const unsigned long long d0 =
                ((own.q & 0xFFFFull) << 16) |
                (((own.q >> 16) & 0xFFFFull) << 48) | tagp;
            const unsigned long long d1 =
                (((own.q >> 32) & 0xFFFFull) << 16) |
                (((own.q >> 48) & 0xFFFFull) << 48) | tagp;
            unsigned long long* hw = (unsigned long long*)
                (hbuf32 + (size_t)(t & 1) * 65536 + (size_t)bg * 512 + jq);
            __hip_atomic_store(hw,     d0, RLX, AGT);
            __hip_atomic_store(hw + 1, d1, RLX, AGT);
        }

        // ---- H[t] store (fire-and-forget; safe: all tags==t seen pre-barrier)
        *(f32x4*)&Hout[(size_t)t * 65536 + (size_t)bg * 512 + jq] = Hv;
    };

    for (int t = 0; t < T_LEN; t += 2) {
        step(t,     ez, en);
        step(t + 1, oz, on);
    }
}

// ---------------------------------------------------------------------------
extern "C" void kernel_launch(void* const* d_in, const int* in_sizes, int n_in,
                              void* d_out, int out_size, void* d_ws, size_t ws_size,
                              hipStream_t stream) {
    (void)in_sizes; (void)n_in; (void)out_size; (void)ws_size;
    const float* seq  = (const float*)d_in[0];
    const float* W_iz = (const float*)d_in[1];
    const float* b_iz = (const float*)d_in[2];
    const float* W_in = (const float*)d_in[3];
    const float* b_in = (const float*)d_in[4];
    const float* W_hz = (const float*)d_in[5];
    const float* b_hz = (const float*)d_in[6];
    const float* W_hn = (const float*)d_in[7];
    const float* b_hn = (const float*)d_in[8];

    char* ws = (char*)d_ws;                                 // total use: ~2.6 MB
    _Float16*     Wci    = (_Float16*)(ws);                 // 1,048,576 B
    _Float16*     Whc    = (_Float16*)(ws + 1048576);       // 1,048,576 B
    float*        bc     = (float*)   (ws + 2097152);       //     4,096 B
    unsigned int* hbuf32 = (unsigned int*)(ws + 2101248);   //   524,288 B tagged

    prep_misc<<<644, 256, 0, stream>>>(W_iz, W_in, W_hz, W_hn,
                                       b_iz, b_in, b_hz, b_hn,
                                       Wci, Whc, bc, hbuf32);
    gemm_proj<<<dim3(512, 8), 256, 0, stream>>>(seq, Wci, bc, (_Float16*)d_out);
    gru_scan<<<32, 512, 0, stream>>>(Whc, (const char*)d_out, (float*)d_out, hbuf32);
}